// Round 4
// baseline (133.067 us; speedup 1.0000x reference)
//
#include <hip/hip_runtime.h>
#include <math.h>

// Problem constants
#define BATCH 1024
#define FEAT  512
#define NT    64
#define DDIM  1024          // CSETSIZE(64) * Nrf(4) * Nrf(4)

typedef __attribute__((ext_vector_type(8))) short  short8;
typedef __attribute__((ext_vector_type(4))) float  floatx4;

// fp32 -> bf16 round-to-nearest-even
__device__ __forceinline__ unsigned short bf16rne(float f) {
    unsigned int u = __float_as_uint(f);
    return (unsigned short)((u + 0x7fffu + ((u >> 16) & 1u)) >> 16);
}
__device__ __forceinline__ short8 pack8(const float4 a, const float4 b) {
    short8 r;
    r[0] = (short)bf16rne(a.x); r[1] = (short)bf16rne(a.y);
    r[2] = (short)bf16rne(a.z); r[3] = (short)bf16rne(a.w);
    r[4] = (short)bf16rne(b.x); r[5] = (short)bf16rne(b.y);
    r[6] = (short)bf16rne(b.z); r[7] = (short)bf16rne(b.w);
    return r;
}

// Output layout (flat):
//   A_real : [0,            BATCH*4096)
//   A_imag : [BATCH*4096,   2*BATCH*4096)
//   D_r_n  : 2*BATCH*4096 + [0, BATCH*1024)
//   D_i_n  : 2*BATCH*4096 + BATCH*1024 + [0, BATCH*1024)
//   CSet   : last 16384 floats
//
// ONE fused kernel, heterogeneous blocks:
//  blocks [0,512):    MFMA bf16 D-GEMM (32 rows x (64 Dr + 64 Di) cols) + in-wave
//                     Frobenius-norm epilogue, direct store of 2*D/V_F.
//                     LDS N-order interleaves Dr/Di per 16-col c-block so each
//                     wave owns complete (Dr,Di) pairs -> norm needs no cross-wave.
//  blocks [512,1536): per-batch-row A_real/A_imag diagonal fill (theta recomputed
//                     from x.W_A in fp32); first 16 of these also copy CSet.
__global__ __launch_bounds__(256) void fused_kernel(
    const float* __restrict__ x,
    const float* __restrict__ W_A,  const float* __restrict__ b_A,
    const float* __restrict__ W_Dr, const float* __restrict__ b_Dr,
    const float* __restrict__ W_Di, const float* __restrict__ b_Di,
    const float* __restrict__ cset,
    float* __restrict__ out)
{
    const int bid = blockIdx.x;
    const int tid = threadIdx.x;

    if (bid < 512) {
        // ---------------- D-GEMM (MFMA bf16) + norm ----------------
        __shared__ __align__(16) unsigned short As[32][32];    // [m][k] bf16
        __shared__ __align__(16) unsigned short Bs[128][32];   // [ldsN][k] bf16

        const int bx   = bid & 15;    // 64-col tile of Dr/Di
        const int by   = bid >> 4;    // 32-row tile (0..31)
        const int row0 = by * 32;
        const int woff = bx * 64;

        // B staging: tasks (n 0..127) x (g 0..3), thread t -> n=t&127, g in {t>>7, (t>>7)+2}
        const int nb = tid & 127;
        const int g0 = tid >> 7;               // 0 or 1
        const float* wsrc = (nb < 64)
            ? (W_Dr + (size_t)(woff + nb) * FEAT)
            : (W_Di + (size_t)(woff + nb - 64) * FEAT);
        // interleave: ldsN = cblock*32 + (Di? 16:0) + (n&15)
        const int ldsN = ((nb & 63) >> 4) * 32 + ((nb < 64) ? 0 : 16) + (nb & 15);

        // A staging: threads 0..127: row = t>>2, k8-group = t&3
        const float* xsrc = x + (size_t)(row0 + (tid >> 2)) * FEAT + (tid & 3) * 8;

        const int lane    = tid & 63;
        const int wv      = tid >> 6;
        const int ln      = lane & 15;
        const int quad    = lane >> 4;
        const int rowbase = (wv & 1) * 16;     // wave's 16-row strip
        const int ctbase  = (wv >> 1) * 4;     // wave's first col-tile (of 8)

        floatx4 acc[4] = {{0,0,0,0},{0,0,0,0},{0,0,0,0},{0,0,0,0}};
        // acc[0]=Dr cb0, acc[1]=Di cb0, acc[2]=Dr cb1, acc[3]=Di cb1 (cb local)

        for (int k0 = 0; k0 < FEAT; k0 += 32) {
            float4 xa0, xa1;
            if (tid < 128) {
                xa0 = *(const float4*)(xsrc + k0);
                xa1 = *(const float4*)(xsrc + k0 + 4);
            }
            const float4 wa0 = *(const float4*)(wsrc + k0 + g0 * 8);
            const float4 wa1 = *(const float4*)(wsrc + k0 + g0 * 8 + 4);
            const float4 wb0 = *(const float4*)(wsrc + k0 + g0 * 8 + 16);
            const float4 wb1 = *(const float4*)(wsrc + k0 + g0 * 8 + 20);

            __syncthreads();   // previous iter's frag reads done
            if (tid < 128)
                *(short8*)&As[tid >> 2][(tid & 3) * 8] = pack8(xa0, xa1);
            *(short8*)&Bs[ldsN][g0 * 8]      = pack8(wa0, wa1);
            *(short8*)&Bs[ldsN][g0 * 8 + 16] = pack8(wb0, wb1);
            __syncthreads();

            const short8 a = *(const short8*)&As[rowbase + ln][quad * 8];
            #pragma unroll
            for (int t = 0; t < 4; ++t) {
                const short8 b = *(const short8*)&Bs[(ctbase + t) * 16 + ln][quad * 8];
                acc[t] = __builtin_amdgcn_mfma_f32_16x16x32_bf16(a, b, acc[t], 0, 0, 0);
            }
        }

        // Epilogue: bias + per-row Frobenius norm + scaled store.
        // C/D layout: col = lane&15, row = quad*4 + reg.
        const size_t drn = (size_t)2 * BATCH * 4096;
        const size_t din = drn + (size_t)BATCH * DDIM;
        #pragma unroll
        for (int p = 0; p < 2; ++p) {
            const int cbg = bx * 4 + (wv >> 1) * 2 + p;   // global c-block 0..63
            const int col = cbg * 16 + ln;                // global D col 0..1023
            const float br = b_Dr[col];
            const float bi = b_Di[col];
            float dr[4], di[4], ps[4];
            #pragma unroll
            for (int i = 0; i < 4; ++i) {
                dr[i] = acc[2 * p][i] + br;
                di[i] = acc[2 * p + 1][i] + bi;
                ps[i] = dr[i] * dr[i] + di[i] * di[i];
            }
            #pragma unroll
            for (int i = 0; i < 4; ++i) {
                ps[i] += __shfl_xor(ps[i], 1);
                ps[i] += __shfl_xor(ps[i], 2);
                ps[i] += __shfl_xor(ps[i], 4);
                ps[i] += __shfl_xor(ps[i], 8);   // sum over the 16 cols of this c-block
            }
            #pragma unroll
            for (int i = 0; i < 4; ++i) {
                const float scale = 2.0f / sqrtf(8.0f * ps[i]);
                const size_t row_g = (size_t)(row0 + rowbase + quad * 4 + i);
                out[drn + row_g * DDIM + col] = dr[i] * scale;
                out[din + row_g * DDIM + col] = di[i] * scale;
            }
        }
    } else {
        // ---------------- A-fill path ----------------
        __shared__ float cosT[NT], sinT[NT];
        const int b = bid - 512;
        const int t = tid >> 2;          // antenna 0..63
        const int q = tid & 3;           // quarter of K

        const float* xr = x   + (size_t)b * FEAT + q * 128;
        const float* wr = W_A + (size_t)t * FEAT + q * 128;
        float sum = 0.f;
        #pragma unroll 8
        for (int i = 0; i < 128; i += 4) {
            const float4 xv = *(const float4*)(xr + i);
            const float4 wv = *(const float4*)(wr + i);
            sum += xv.x * wv.x + xv.y * wv.y + xv.z * wv.z + xv.w * wv.w;
        }
        sum += __shfl_xor(sum, 1);
        sum += __shfl_xor(sum, 2);
        if (q == 0) {
            float s, c;
            sincosf(sum + b_A[t], &s, &c);
            cosT[t] = c; sinT[t] = s;
        }
        __syncthreads();

        float* ar = out + (size_t)b * 4096;
        float* ai = out + (size_t)BATCH * 4096 + (size_t)b * 4096;
        #pragma unroll
        for (int it = 0; it < 4; ++it) {
            const int idx = tid + it * 256;   // float4 chunk 0..1023
            const int tt = idx >> 4;          // row in 64x64
            const int j0 = (idx & 15) * 4;    // first col of chunk
            float4 vr = {0.f, 0.f, 0.f, 0.f};
            float4 vi = {0.f, 0.f, 0.f, 0.f};
            if (tt >= j0 && tt < j0 + 4) {
                ((float*)&vr)[tt - j0] = cosT[tt];
                ((float*)&vi)[tt - j0] = sinT[tt];
            }
            ((float4*)ar)[idx] = vr;
            ((float4*)ai)[idx] = vi;
        }

        if (b < 16) {
            const size_t base = (size_t)2 * BATCH * 4096 + (size_t)2 * BATCH * DDIM;
            ((float4*)(out + base))[b * 256 + tid] = ((const float4*)cset)[b * 256 + tid];
        }
    }
}

extern "C" void kernel_launch(void* const* d_in, const int* in_sizes, int n_in,
                              void* d_out, int out_size, void* d_ws, size_t ws_size,
                              hipStream_t stream) {
    const float* x    = (const float*)d_in[0];
    const float* W_A  = (const float*)d_in[1];
    const float* b_A  = (const float*)d_in[2];
    const float* W_Dr = (const float*)d_in[3];
    const float* b_Dr = (const float*)d_in[4];
    const float* W_Di = (const float*)d_in[5];
    const float* b_Di = (const float*)d_in[6];
    const float* CSet = (const float*)d_in[7];
    float* out = (float*)d_out;

    fused_kernel<<<1536, 256, 0, stream>>>(x, W_A, b_A, W_Dr, b_Dr, W_Di, b_Di,
                                           CSet, out);
}

// Round 5
// 121.988 us; speedup vs baseline: 1.0908x; 1.0908x over previous
//
#include <hip/hip_runtime.h>
#include <math.h>

// Problem constants
#define BATCH 1024
#define FEAT  512
#define NT    64
#define DDIM  1024          // CSETSIZE(64) * Nrf(4) * Nrf(4)

typedef __attribute__((ext_vector_type(8))) short  short8;
typedef __attribute__((ext_vector_type(4))) short  short4v;
typedef __attribute__((ext_vector_type(4))) float  floatx4;

// fp32 -> bf16 round-to-nearest-even
__device__ __forceinline__ unsigned short bf16rne(float f) {
    unsigned int u = __float_as_uint(f);
    return (unsigned short)((u + 0x7fffu + ((u >> 16) & 1u)) >> 16);
}
__device__ __forceinline__ short4v pack4(const float4 a) {
    short4v r;
    r[0] = (short)bf16rne(a.x); r[1] = (short)bf16rne(a.y);
    r[2] = (short)bf16rne(a.z); r[3] = (short)bf16rne(a.w);
    return r;
}

// Output layout (flat):
//   A_real : [0,            BATCH*4096)
//   A_imag : [BATCH*4096,   2*BATCH*4096)
//   D_r_n  : 2*BATCH*4096 + [0, BATCH*1024)
//   D_i_n  : 2*BATCH*4096 + BATCH*1024 + [0, BATCH*1024)
//   CSet   : last 16384 floats
//
// ONE fused kernel, heterogeneous blocks. ALL global loads are coalesced:
// consecutive lanes read consecutive float4 within one W/x row (8 cache
// lines per wave-instr), fixing the TA serialization that dominated r3/r4.
//  blocks [0,512):    MFMA bf16 D-GEMM (32 rows x (64 Dr + 64 Di)) + in-wave
//                     Frobenius-norm epilogue. bf16 LDS rows padded to 40
//                     shorts (80B) -> ~conflict-free b128 frag reads.
//  blocks [512,1536): per-batch A_real/A_imag diagonal fill; theta recomputed
//                     from x.W_A with W_A chunks staged through LDS.
__global__ __launch_bounds__(256) void fused_kernel(
    const float* __restrict__ x,
    const float* __restrict__ W_A,  const float* __restrict__ b_A,
    const float* __restrict__ W_Dr, const float* __restrict__ b_Dr,
    const float* __restrict__ W_Di, const float* __restrict__ b_Di,
    const float* __restrict__ cset,
    float* __restrict__ out)
{
    __shared__ __align__(16) unsigned char smem[17920];
    const int bid = blockIdx.x;
    const int tid = threadIdx.x;

    if (bid < 512) {
        // ---------------- D-GEMM (MFMA bf16) + norm ----------------
        unsigned short (*As)[40] = (unsigned short (*)[40])smem;          // 32 rows
        unsigned short (*Bs)[40] = (unsigned short (*)[40])(smem + 2560); // 128 rows

        const int bx   = bid & 15;    // 64-col tile of Dr/Di
        const int by   = bid >> 4;    // 32-row tile
        const int row0 = by * 32;
        const int woff = bx * 64;

        // coalesced staging map: f = float4-in-row, rl = row-in-round
        const int f  = tid & 7;       // 0..7  (8 x float4 = 32 floats)
        const int rl = tid >> 3;      // 0..31

        const float* xsrc = x + (size_t)(row0 + rl) * FEAT + f * 4;
        const float* wsrc[4];
        int ldsN[4];
        #pragma unroll
        for (int rr = 0; rr < 4; ++rr) {
            const int n = rr * 32 + rl;          // B-tile row 0..127
            wsrc[rr] = ((n < 64) ? W_Dr + (size_t)(woff + n) * FEAT
                                 : W_Di + (size_t)(woff + n - 64) * FEAT) + f * 4;
            // interleave Dr/Di per 16-col c-block so each wave owns (Dr,Di) pairs
            ldsN[rr] = ((n & 63) >> 4) * 32 + ((n < 64) ? 0 : 16) + (n & 15);
        }

        const int lane    = tid & 63;
        const int wv      = tid >> 6;
        const int ln      = lane & 15;
        const int quad    = lane >> 4;
        const int rowbase = (wv & 1) * 16;
        const int ctbase  = (wv >> 1) * 4;

        floatx4 acc[4] = {{0,0,0,0},{0,0,0,0},{0,0,0,0},{0,0,0,0}};

        for (int k0 = 0; k0 < FEAT; k0 += 32) {
            const float4 xa = *(const float4*)(xsrc + k0);
            float4 wb[4];
            #pragma unroll
            for (int rr = 0; rr < 4; ++rr)
                wb[rr] = *(const float4*)(wsrc[rr] + k0);

            __syncthreads();   // previous iter's frag reads done
            *(short4v*)&As[rl][f * 4] = pack4(xa);
            #pragma unroll
            for (int rr = 0; rr < 4; ++rr)
                *(short4v*)&Bs[ldsN[rr]][f * 4] = pack4(wb[rr]);
            __syncthreads();

            const short8 a = *(const short8*)&As[rowbase + ln][quad * 8];
            #pragma unroll
            for (int t = 0; t < 4; ++t) {
                const short8 b = *(const short8*)&Bs[(ctbase + t) * 16 + ln][quad * 8];
                acc[t] = __builtin_amdgcn_mfma_f32_16x16x32_bf16(a, b, acc[t], 0, 0, 0);
            }
        }

        // Epilogue: bias + per-row Frobenius norm + scaled store.
        // C/D layout: col = lane&15, row = quad*4 + reg.
        const size_t drn = (size_t)2 * BATCH * 4096;
        const size_t din = drn + (size_t)BATCH * DDIM;
        #pragma unroll
        for (int p = 0; p < 2; ++p) {
            const int cbg = bx * 4 + (wv >> 1) * 2 + p;   // global c-block 0..63
            const int col = cbg * 16 + ln;
            const float br = b_Dr[col];
            const float bi = b_Di[col];
            float dr[4], di[4], ps[4];
            #pragma unroll
            for (int i = 0; i < 4; ++i) {
                dr[i] = acc[2 * p][i] + br;
                di[i] = acc[2 * p + 1][i] + bi;
                ps[i] = dr[i] * dr[i] + di[i] * di[i];
            }
            #pragma unroll
            for (int i = 0; i < 4; ++i) {
                ps[i] += __shfl_xor(ps[i], 1);
                ps[i] += __shfl_xor(ps[i], 2);
                ps[i] += __shfl_xor(ps[i], 4);
                ps[i] += __shfl_xor(ps[i], 8);   // sum over the 16 cols of c-block
            }
            #pragma unroll
            for (int i = 0; i < 4; ++i) {
                const float scale = 2.0f / sqrtf(8.0f * ps[i]);
                const size_t row_g = (size_t)(row0 + rowbase + quad * 4 + i);
                out[drn + row_g * DDIM + col] = dr[i] * scale;
                out[din + row_g * DDIM + col] = di[i] * scale;
            }
        }
    } else {
        // ---------------- A-fill path ----------------
        float (*WAs)[68] = (float (*)[68])smem;     // 64 rows x 64-float chunk (+pad)
        float* cosT = (float*)(smem + 17408);
        float* sinT = cosT + NT;

        const int b  = bid - 512;
        const int t  = tid >> 2;          // antenna 0..63
        const int q  = tid & 3;           // k quarter-of-chunk
        const int sf = tid & 15;          // stage: float4 within 64-float chunk
        const int sr = tid >> 4;          // stage: row in round (16 rows/round)

        float sum = 0.f;
        for (int c = 0; c < 8; ++c) {     // 8 chunks of 64 k
            __syncthreads();              // protect WAs from prev chunk readers
            #pragma unroll
            for (int rr = 0; rr < 4; ++rr) {
                const int row = rr * 16 + sr;
                *(float4*)&WAs[row][sf * 4] =
                    *(const float4*)(W_A + (size_t)row * FEAT + c * 64 + sf * 4);
            }
            __syncthreads();
            const float* xs = x + (size_t)b * FEAT + c * 64 + q * 16;
            #pragma unroll
            for (int i = 0; i < 4; ++i) {
                const float4 wv4 = *(const float4*)&WAs[t][q * 16 + i * 4];
                const float4 xv  = *(const float4*)(xs + i * 4);
                sum += wv4.x * xv.x + wv4.y * xv.y + wv4.z * xv.z + wv4.w * xv.w;
            }
        }
        sum += __shfl_xor(sum, 1);
        sum += __shfl_xor(sum, 2);
        if (q == 0) {
            float s, cc;
            sincosf(sum + b_A[t], &s, &cc);
            cosT[t] = cc; sinT[t] = s;
        }
        __syncthreads();

        float* ar = out + (size_t)b * 4096;
        float* ai = out + (size_t)BATCH * 4096 + (size_t)b * 4096;
        #pragma unroll
        for (int it = 0; it < 4; ++it) {
            const int idx = tid + it * 256;   // float4 chunk 0..1023
            const int tt = idx >> 4;          // row in 64x64
            const int j0 = (idx & 15) * 4;    // first col of chunk
            float4 vr = {0.f, 0.f, 0.f, 0.f};
            float4 vi = {0.f, 0.f, 0.f, 0.f};
            if (tt >= j0 && tt < j0 + 4) {
                ((float*)&vr)[tt - j0] = cosT[tt];
                ((float*)&vi)[tt - j0] = sinT[tt];
            }
            ((float4*)ar)[idx] = vr;
            ((float4*)ai)[idx] = vi;
        }

        if (b < 16) {
            const size_t base = (size_t)2 * BATCH * 4096 + (size_t)2 * BATCH * DDIM;
            ((float4*)(out + base))[b * 256 + tid] = ((const float4*)cset)[b * 256 + tid];
        }
    }
}

extern "C" void kernel_launch(void* const* d_in, const int* in_sizes, int n_in,
                              void* d_out, int out_size, void* d_ws, size_t ws_size,
                              hipStream_t stream) {
    const float* x    = (const float*)d_in[0];
    const float* W_A  = (const float*)d_in[1];
    const float* b_A  = (const float*)d_in[2];
    const float* W_Dr = (const float*)d_in[3];
    const float* b_Dr = (const float*)d_in[4];
    const float* W_Di = (const float*)d_in[5];
    const float* b_Di = (const float*)d_in[6];
    const float* CSet = (const float*)d_in[7];
    float* out = (float*)d_out;

    fused_kernel<<<1536, 256, 0, stream>>>(x, W_A, b_A, W_Dr, b_Dr, W_Di, b_Di,
                                           CSet, out);
}

// Round 6
// 112.492 us; speedup vs baseline: 1.1829x; 1.0844x over previous
//
#include <hip/hip_runtime.h>
#include <math.h>

// Problem constants
#define BATCH 1024
#define FEAT  512
#define NT    64
#define DDIM  1024          // CSETSIZE(64) * Nrf(4) * Nrf(4)

typedef __attribute__((ext_vector_type(8))) short  short8;
typedef __attribute__((ext_vector_type(4))) short  short4v;
typedef __attribute__((ext_vector_type(4))) float  floatx4;

// fp32 -> bf16 round-to-nearest-even
__device__ __forceinline__ unsigned short bf16rne(float f) {
    unsigned int u = __float_as_uint(f);
    return (unsigned short)((u + 0x7fffu + ((u >> 16) & 1u)) >> 16);
}
__device__ __forceinline__ short4v pack4(const float4 a) {
    short4v r;
    r[0] = (short)bf16rne(a.x); r[1] = (short)bf16rne(a.y);
    r[2] = (short)bf16rne(a.z); r[3] = (short)bf16rne(a.w);
    return r;
}

// Output layout (flat):
//   A_real : [0,            BATCH*4096)
//   A_imag : [BATCH*4096,   2*BATCH*4096)
//   D_r_n  : 2*BATCH*4096 + [0, BATCH*1024)
//   D_i_n  : 2*BATCH*4096 + BATCH*1024 + [0, BATCH*1024)
//   CSet   : last 16384 floats

// ===========================================================================
// K1: MFMA bf16 GEMM.
//   blocks [0,512):   D path. Tile = 64 b-rows x (32 Dr cols + 32 Di cols).
//                     by = bid>>5 (row tile), bx = bid&31 (col tile, woff=bx*32).
//                     LDS B interleave per 16-col c-block: [cb0Dr|cb0Di|cb1Dr|cb1Di]
//                     so each wave holds complete (Dr,Di) pairs; per-row Frobenius
//                     norm via shfl_xor(1,2,4,8); writes 2*D/V_F straight to out.
//   blocks [512,528): theta path. Tile = 64 b-rows x 64 antennas (B = all W_A).
//                     Writes theta (fp32) to ws[b*64+t] for K2.
// Each thread stages exactly 4 float4 per K-iter (A rows r,r+32; B rows r,r+32),
// prefetched one iteration ahead in registers so the load latency overlaps
// MFMA + both barriers instead of serializing (the r5 failure mode: VGPR=36
// forced load->wait->pack chains).
// ===========================================================================
__global__ __launch_bounds__(256) void k1_gemm(
    const float* __restrict__ x,
    const float* __restrict__ W_A,  const float* __restrict__ b_A,
    const float* __restrict__ W_Dr, const float* __restrict__ b_Dr,
    const float* __restrict__ W_Di, const float* __restrict__ b_Di,
    float* __restrict__ out, float* __restrict__ theta_ws)
{
    __shared__ __align__(16) unsigned short As[64][40];   // 40-short stride: <=2-way (free)
    __shared__ __align__(16) unsigned short Bs[64][40];

    const int bid  = blockIdx.x;
    const int tid  = threadIdx.x;
    const int lane = tid & 63;
    const int wv   = tid >> 6;
    const int ln   = lane & 15;
    const int quad = lane >> 4;

    // staging map: row r in 0..31 (handles rows r and r+32), float4 slot f in 0..7
    const int f = tid & 7;
    const int r = tid >> 3;

    const bool isD = (bid < 512);
    int row0, woff, ldsn0, ldsn1;
    const float *arow0, *arow1, *brow0, *brow1;

    if (isD) {
        const int by = bid >> 5;
        const int bx = bid & 31;
        row0 = by * 64;
        woff = bx * 32;
        brow0 = W_Dr + (size_t)(woff + r) * FEAT;              // Dr rows
        brow1 = W_Di + (size_t)(woff + r) * FEAT;              // Di rows
        ldsn0 = (r >> 4) * 32 + (r & 15);                      // cb*32 + pos (Dr)
        ldsn1 = (r >> 4) * 32 + 16 + (r & 15);                 // cb*32 + 16 + pos (Di)
    } else {
        const int by = bid - 512;
        row0 = by * 64;
        woff = 0;
        brow0 = W_A + (size_t)r * FEAT;
        brow1 = W_A + (size_t)(r + 32) * FEAT;
        ldsn0 = r;
        ldsn1 = r + 32;
    }
    arow0 = x + (size_t)(row0 + r) * FEAT;
    arow1 = x + (size_t)(row0 + r + 32) * FEAT;

    // prefetch iter 0
    float4 pa0 = *(const float4*)(arow0 + f * 4);
    float4 pa1 = *(const float4*)(arow1 + f * 4);
    float4 pb0 = *(const float4*)(brow0 + f * 4);
    float4 pb1 = *(const float4*)(brow1 + f * 4);

    floatx4 acc[4] = {{0,0,0,0},{0,0,0,0},{0,0,0,0},{0,0,0,0}};

    #pragma unroll 1
    for (int it = 0; it < 16; ++it) {
        __syncthreads();                 // prev iter's frag reads done
        *(short4v*)&As[r][f * 4]        = pack4(pa0);
        *(short4v*)&As[r + 32][f * 4]   = pack4(pa1);
        *(short4v*)&Bs[ldsn0][f * 4]    = pack4(pb0);
        *(short4v*)&Bs[ldsn1][f * 4]    = pack4(pb1);
        __syncthreads();

        if (it < 15) {                   // issue next-iter loads; consumed after
            const int ko = (it + 1) * 32 + f * 4;   // compute + 2 barriers
            pa0 = *(const float4*)(arow0 + ko);
            pa1 = *(const float4*)(arow1 + ko);
            pb0 = *(const float4*)(brow0 + ko);
            pb1 = *(const float4*)(brow1 + ko);
        }

        const short8 a = *(const short8*)&As[wv * 16 + ln][quad * 8];
        #pragma unroll
        for (int t = 0; t < 4; ++t) {
            const short8 b = *(const short8*)&Bs[t * 16 + ln][quad * 8];
            acc[t] = __builtin_amdgcn_mfma_f32_16x16x32_bf16(a, b, acc[t], 0, 0, 0);
        }
    }

    // C/D layout: col = lane&15, row = quad*4 + reg.
    if (isD) {
        const size_t drn = (size_t)2 * BATCH * 4096;
        const size_t din = drn + (size_t)BATCH * DDIM;
        #pragma unroll
        for (int p = 0; p < 2; ++p) {
            const int colg = woff + p * 16 + ln;     // global D col
            const float br = b_Dr[colg];
            const float bi = b_Di[colg];
            float dr[4], di[4], ps[4];
            #pragma unroll
            for (int i = 0; i < 4; ++i) {
                dr[i] = acc[2 * p][i] + br;
                di[i] = acc[2 * p + 1][i] + bi;
                ps[i] = dr[i] * dr[i] + di[i] * di[i];
            }
            #pragma unroll
            for (int i = 0; i < 4; ++i) {
                ps[i] += __shfl_xor(ps[i], 1);
                ps[i] += __shfl_xor(ps[i], 2);
                ps[i] += __shfl_xor(ps[i], 4);
                ps[i] += __shfl_xor(ps[i], 8);       // sum over 16 cols of c-block
            }
            #pragma unroll
            for (int i = 0; i < 4; ++i) {
                const float scale = 2.0f / sqrtf(8.0f * ps[i]);
                const size_t row_g = (size_t)(row0 + wv * 16 + quad * 4 + i);
                out[drn + row_g * DDIM + colg] = dr[i] * scale;
                out[din + row_g * DDIM + colg] = di[i] * scale;
            }
        }
    } else {
        #pragma unroll
        for (int t = 0; t < 4; ++t) {
            const int colg = t * 16 + ln;            // antenna 0..63
            const float ba = b_A[colg];
            #pragma unroll
            for (int i = 0; i < 4; ++i) {
                const int row_g = row0 + wv * 16 + quad * 4 + i;
                theta_ws[row_g * NT + colg] = acc[t][i] + ba;
            }
        }
    }
}

// ===========================================================================
// K2: streaming fill. No LDS, no barriers.
//   blocks [0,4096):    A_real/A_imag. Block beta: b = beta>>2, 16 antenna rows
//                       (beta&3)*16... Thread (tl=tid>>4, j=tid&15) writes the
//                       64-float chunk row t=rowgrp*16+tl, cols j*4..j*4+3 of
//                       both matrices (zeros + diag patch from sincos(theta)).
//                       Wave = 4 rows x 256B contiguous per store instr.
//   blocks [4096,4112): CSet pass-through.
// ===========================================================================
__global__ __launch_bounds__(256) void k2_fill(
    const float* __restrict__ theta_ws,
    const float* __restrict__ cset,
    float* __restrict__ out)
{
    const int beta = blockIdx.x;
    const int tid  = threadIdx.x;

    if (beta < 4096) {
        const int b  = beta >> 2;
        const int rg = beta & 3;
        const int t  = rg * 16 + (tid >> 4);   // antenna row 0..63
        const int j  = tid & 15;               // float4 col chunk

        const float th = theta_ws[b * NT + t];
        float s, c;
        sincosf(th, &s, &c);

        float4 vr = {0.f, 0.f, 0.f, 0.f};
        float4 vi = {0.f, 0.f, 0.f, 0.f};
        if ((t >> 2) == j) {
            ((float*)&vr)[t & 3] = c;
            ((float*)&vi)[t & 3] = s;
        }
        const size_t off = (size_t)b * 4096 + t * 64 + j * 4;
        *(float4*)(out + off) = vr;
        *(float4*)(out + (size_t)BATCH * 4096 + off) = vi;
    } else {
        const int cb = beta - 4096;            // 0..15
        const size_t base = (size_t)2 * BATCH * 4096 + (size_t)2 * BATCH * DDIM;
        ((float4*)(out + base))[cb * 256 + tid] = ((const float4*)cset)[cb * 256 + tid];
    }
}

extern "C" void kernel_launch(void* const* d_in, const int* in_sizes, int n_in,
                              void* d_out, int out_size, void* d_ws, size_t ws_size,
                              hipStream_t stream) {
    const float* x    = (const float*)d_in[0];
    const float* W_A  = (const float*)d_in[1];
    const float* b_A  = (const float*)d_in[2];
    const float* W_Dr = (const float*)d_in[3];
    const float* b_Dr = (const float*)d_in[4];
    const float* W_Di = (const float*)d_in[5];
    const float* b_Di = (const float*)d_in[6];
    const float* CSet = (const float*)d_in[7];
    float* out   = (float*)d_out;
    float* theta = (float*)d_ws;   // BATCH*NT fp32 = 256 KB

    k1_gemm<<<528, 256, 0, stream>>>(x, W_A, b_A, W_Dr, b_Dr, W_Di, b_Di,
                                     out, theta);
    k2_fill<<<4112, 256, 0, stream>>>(theta, CSet, out);
}

// Round 7
// 107.059 us; speedup vs baseline: 1.2429x; 1.0507x over previous
//
#include <hip/hip_runtime.h>
#include <math.h>

// Problem constants
#define BATCH 1024
#define FEAT  512
#define NT    64
#define DDIM  1024          // CSETSIZE(64) * Nrf(4) * Nrf(4)

typedef __attribute__((ext_vector_type(8))) short  short8;
typedef __attribute__((ext_vector_type(4))) float  floatx4;

// ws layout (bytes):
//   A-image : 16 row-tiles x 8 k-tiles x 8 KB  = 1,048,576
//   B-image : 33 col-tiles x 8 k-tiles x 8 KB  = 2,162,688  (Dr/Di interleaved + W_A)
//   theta   : BATCH*NT fp32 at 3,276,800
#define AIMG_OFF  0
#define BIMG_OFF  1048576
#define THETA_OFF 3276800

// fp32 -> bf16 round-to-nearest-even
__device__ __forceinline__ unsigned short bf16rne(float f) {
    unsigned int u = __float_as_uint(f);
    return (unsigned short)((u + 0x7fffu + ((u >> 16) & 1u)) >> 16);
}

__device__ __forceinline__ void gld16(const unsigned char* g, unsigned char* l) {
    __builtin_amdgcn_global_load_lds(
        (const __attribute__((address_space(1))) unsigned int*)g,
        (__attribute__((address_space(3))) unsigned int*)l, 16, 0, 0);
}

// ===========================================================================
// K0: convert fp32 inputs to bf16 "LDS-image" tiles (8 KB = 64 rows x 64 k,
// 16B chunks XOR-swizzled: chunk c of row r stored at position c^(r&7)).
// B-image col-tile ct<32 interleaves Dr/Di per 16-col c-block:
//   LDS row n: g=n>>5, h=(n>>4)&1, pos=n&15 -> (h?W_Di:W_Dr) col ct*32+g*16+pos.
// ct==32 holds W_A rows 0..63 (theta tile).
// ===========================================================================
__global__ __launch_bounds__(256) void k0_convert(
    const float* __restrict__ x,
    const float* __restrict__ W_A,
    const float* __restrict__ W_Dr,
    const float* __restrict__ W_Di,
    unsigned char* __restrict__ ws)
{
    unsigned short* aimg = (unsigned short*)(ws + AIMG_OFF);
    unsigned short* bimg = (unsigned short*)(ws + BIMG_OFF);
    const int gtid = blockIdx.x * 256 + threadIdx.x;   // 65536 threads

    for (int idx = gtid; idx < 200704; idx += 65536) {
        const float* src;
        unsigned short* dst;
        if (idx < 65536) {                 // A-image: x
            const int rt = idx >> 12, kb = (idx >> 9) & 7;
            const int r  = (idx >> 3) & 63, c = idx & 7;
            src = x + ((size_t)(rt * 64 + r) * FEAT + kb * 64 + c * 8);
            dst = aimg + ((rt * 8 + kb) * 4096 + r * 64 + ((c ^ (r & 7)) * 8));
        } else {                           // B-image: W_Dr/W_Di interleaved, W_A
            const int j  = idx - 65536;
            const int ct = j >> 12, kb = (j >> 9) & 7;
            const int n  = (j >> 3) & 63, c = j & 7;
            const float* wrow;
            if (ct < 32) {
                const int g = n >> 5, h = (n >> 4) & 1, pos = n & 15;
                wrow = (h ? W_Di : W_Dr) + (size_t)(ct * 32 + g * 16 + pos) * FEAT;
            } else {
                wrow = W_A + (size_t)n * FEAT;
            }
            src = wrow + kb * 64 + c * 8;
            dst = bimg + ((ct * 8 + kb) * 4096 + n * 64 + ((c ^ (n & 7)) * 8));
        }
        const float4 v0 = *(const float4*)src;
        const float4 v1 = *(const float4*)(src + 4);
        short8 o;
        o[0] = (short)bf16rne(v0.x); o[1] = (short)bf16rne(v0.y);
        o[2] = (short)bf16rne(v0.z); o[3] = (short)bf16rne(v0.w);
        o[4] = (short)bf16rne(v1.x); o[5] = (short)bf16rne(v1.y);
        o[6] = (short)bf16rne(v1.z); o[7] = (short)bf16rne(v1.w);
        *(short8*)dst = o;
    }
}

// ===========================================================================
// K1: MFMA bf16 GEMM from pre-built images. Tile = 64 batch rows x 64 LDS cols.
// Grid 528: rt = bid&15, ct = bid>>4 (0..31 = D tiles, 32 = theta tile).
// Staging = pure global_load_lds DMA (no VALU), double-buffered, 1 barrier/step.
// Epilogue: D tiles -> bias + per-row Frobenius norm (shfl) + 2*D/V_F stores;
// theta tile -> theta_ws.
// ===========================================================================
__global__ __launch_bounds__(256) void k1_gemm(
    const unsigned char* __restrict__ ws,
    const float* __restrict__ b_A,
    const float* __restrict__ b_Dr, const float* __restrict__ b_Di,
    float* __restrict__ out, float* __restrict__ theta_ws)
{
    __shared__ __align__(16) unsigned char smem[32768];   // 2 bufs x (8KB A + 8KB B)

    const int bid  = blockIdx.x;
    const int rt   = bid & 15;
    const int ct   = bid >> 4;        // 0..32
    const int tid  = threadIdx.x;
    const int lane = tid & 63;
    const int wv   = tid >> 6;
    const int ln   = lane & 15;
    const int quad = lane >> 4;
    const int row0 = rt * 64;

    const unsigned char* Atiles = ws + AIMG_OFF + (size_t)rt * 8 * 8192;
    const unsigned char* Btiles = ws + BIMG_OFF + (size_t)ct * 8 * 8192;

    // per-wave DMA chunks: 2x1KB of A + 2x1KB of B per k-step
    const int g0 = (wv * 2 + 0) * 1024;
    const int g1 = (wv * 2 + 1) * 1024;
    const int lo = lane * 16;

    floatx4 acc[4] = {{0,0,0,0},{0,0,0,0},{0,0,0,0},{0,0,0,0}};

    // prefetch kb=0 into buf 0
    {
        unsigned char* La = smem;
        unsigned char* Lb = smem + 8192;
        gld16(Atiles + g0 + lo, La + g0);
        gld16(Atiles + g1 + lo, La + g1);
        gld16(Btiles + g0 + lo, Lb + g0);
        gld16(Btiles + g1 + lo, Lb + g1);
    }

    const int rowOffA = (wv * 16 + ln) * 128;
    const int swz = ln & 7;
    int cur = 0;

    #pragma unroll 1
    for (int kb = 0; kb < 8; ++kb) {
        __syncthreads();   // drains vmcnt(0): buf 'cur' staged; prev frag reads done
        if (kb < 7) {      // prefetch next k-step into the other buffer
            const unsigned char* At = Atiles + (kb + 1) * 8192;
            const unsigned char* Bt = Btiles + (kb + 1) * 8192;
            unsigned char* La = smem + (cur ^ 1) * 16384;
            unsigned char* Lb = La + 8192;
            gld16(At + g0 + lo, La + g0);
            gld16(At + g1 + lo, La + g1);
            gld16(Bt + g0 + lo, Lb + g0);
            gld16(Bt + g1 + lo, Lb + g1);
        }
        const unsigned char* La = smem + cur * 16384;
        const unsigned char* Lb = La + 8192;
        #pragma unroll
        for (int ks = 0; ks < 2; ++ks) {
            const int ca = ((ks * 4 + quad) ^ swz) * 16;
            const short8 a = *(const short8*)(La + rowOffA + ca);
            #pragma unroll
            for (int t = 0; t < 4; ++t) {
                const short8 b = *(const short8*)(Lb + (t * 16 + ln) * 128 + ca);
                acc[t] = __builtin_amdgcn_mfma_f32_16x16x32_bf16(a, b, acc[t], 0, 0, 0);
            }
        }
        cur ^= 1;
    }

    // C/D layout: col = lane&15, row = quad*4 + reg.
    if (ct < 32) {
        const size_t drn = (size_t)2 * BATCH * 4096;
        const size_t din = drn + (size_t)BATCH * DDIM;
        const int woff = ct * 32;
        #pragma unroll
        for (int p = 0; p < 2; ++p) {
            const int colg = woff + p * 16 + ln;     // global D col
            const float br = b_Dr[colg];
            const float bi = b_Di[colg];
            float dr[4], di[4], ps[4];
            #pragma unroll
            for (int i = 0; i < 4; ++i) {
                dr[i] = acc[2 * p][i] + br;
                di[i] = acc[2 * p + 1][i] + bi;
                ps[i] = dr[i] * dr[i] + di[i] * di[i];
            }
            #pragma unroll
            for (int i = 0; i < 4; ++i) {
                ps[i] += __shfl_xor(ps[i], 1);
                ps[i] += __shfl_xor(ps[i], 2);
                ps[i] += __shfl_xor(ps[i], 4);
                ps[i] += __shfl_xor(ps[i], 8);       // sum over 16 cols of c-block
            }
            #pragma unroll
            for (int i = 0; i < 4; ++i) {
                const float scale = 2.0f / sqrtf(8.0f * ps[i]);
                const size_t row_g = (size_t)(row0 + wv * 16 + quad * 4 + i);
                out[drn + row_g * DDIM + colg] = dr[i] * scale;
                out[din + row_g * DDIM + colg] = di[i] * scale;
            }
        }
    } else {
        #pragma unroll
        for (int t = 0; t < 4; ++t) {
            const int colg = t * 16 + ln;            // antenna 0..63
            const float ba = b_A[colg];
            #pragma unroll
            for (int i = 0; i < 4; ++i) {
                const int row_g = row0 + wv * 16 + quad * 4 + i;
                theta_ws[row_g * NT + colg] = acc[t][i] + ba;
            }
        }
    }
}

// ===========================================================================
// K2: streaming fill. No LDS, no barriers.
//   blocks [0,4096):    A_real/A_imag diagonal matrices from sincos(theta).
//   blocks [4096,4112): CSet pass-through.
// ===========================================================================
__global__ __launch_bounds__(256) void k2_fill(
    const float* __restrict__ theta_ws,
    const float* __restrict__ cset,
    float* __restrict__ out)
{
    const int beta = blockIdx.x;
    const int tid  = threadIdx.x;

    if (beta < 4096) {
        const int b  = beta >> 2;
        const int rg = beta & 3;
        const int t  = rg * 16 + (tid >> 4);   // antenna row 0..63
        const int j  = tid & 15;               // float4 col chunk

        const float th = theta_ws[b * NT + t];
        float s, c;
        sincosf(th, &s, &c);

        float4 vr = {0.f, 0.f, 0.f, 0.f};
        float4 vi = {0.f, 0.f, 0.f, 0.f};
        if ((t >> 2) == j) {
            ((float*)&vr)[t & 3] = c;
            ((float*)&vi)[t & 3] = s;
        }
        const size_t off = (size_t)b * 4096 + t * 64 + j * 4;
        *(float4*)(out + off) = vr;
        *(float4*)(out + (size_t)BATCH * 4096 + off) = vi;
    } else {
        const int cb = beta - 4096;            // 0..15
        const size_t base = (size_t)2 * BATCH * 4096 + (size_t)2 * BATCH * DDIM;
        ((float4*)(out + base))[cb * 256 + tid] = ((const float4*)cset)[cb * 256 + tid];
    }
}

extern "C" void kernel_launch(void* const* d_in, const int* in_sizes, int n_in,
                              void* d_out, int out_size, void* d_ws, size_t ws_size,
                              hipStream_t stream) {
    const float* x    = (const float*)d_in[0];
    const float* W_A  = (const float*)d_in[1];
    const float* b_A  = (const float*)d_in[2];
    const float* W_Dr = (const float*)d_in[3];
    const float* b_Dr = (const float*)d_in[4];
    const float* W_Di = (const float*)d_in[5];
    const float* b_Di = (const float*)d_in[6];
    const float* CSet = (const float*)d_in[7];
    float* out = (float*)d_out;
    unsigned char* ws = (unsigned char*)d_ws;
    float* theta = (float*)(ws + THETA_OFF);

    k0_convert<<<256, 256, 0, stream>>>(x, W_A, W_Dr, W_Di, ws);
    k1_gemm<<<528, 256, 0, stream>>>(ws, b_A, b_Dr, b_Di, out, theta);
    k2_fill<<<4112, 256, 0, stream>>>(theta, CSet, out);
}